// Round 5
// baseline (131.165 us; speedup 1.0000x reference)
//
#include <hip/hip_runtime.h>
#include <hip/hip_cooperative_groups.h>
#include <math.h>

namespace cg = cooperative_groups;

#define MM 512
#define NN 1024
#define BB 64
#define SS 50
#define ETA 0.1f

// One cooperative kernel, 4 phases, 3 grid syncs.
// grid 256 x 512 threads (8 waves). LDS: 4+4+4+8+32 = 52KB -> >=3 blocks/CU
// capacity, co-residency at 1 block/CU guaranteed by cooperative launch.
__global__ __launch_bounds__(512, 2) void k_fused(
    const float* __restrict__ X,   // (N,B)
    const float* __restrict__ Y,   // (B,M)
    const float* __restrict__ A,   // (M,N)
    const float* __restrict__ W,   // (N)
    float* __restrict__ R,         // (M,B) ws
    float* __restrict__ z_t,       // (B,N) ws
    float* __restrict__ H1_t,      // (B,N) ws
    float* __restrict__ c_part,    // (4,B,N) ws
    float* __restrict__ out) {     // (N,B)
  cg::grid_group grid = cg::this_grid();
  const int bid = blockIdx.x;   // 0..255
  const int t = threadIdx.x;    // 0..511
  const int l = t & 63;
  const int w = t >> 6;

  __shared__ float p1[8][2][BB];
  __shared__ float p2[2][4][128];
  __shared__ __align__(16) float4 z4[NN / 4];
  __shared__ __align__(16) float2 zc_s[NN];
  __shared__ float mpart[8][NN];

  // ---------- Phase 1: R[m,b] = Y[b,m] - sum_n A[m,n]*X[n,b] ----------
  {
    const int m0 = bid * 2;
    const float* __restrict__ Xp = X + w * 128 * BB + l;
    const float* __restrict__ A0 = A + (size_t)m0 * NN + w * 128;
    const float* __restrict__ A1 = A0 + NN;
    float r0a = 0.f, r0b = 0.f, r1a = 0.f, r1b = 0.f;
    #pragma unroll 8
    for (int i = 0; i < 128; i += 4) {
      const float x0 = Xp[(i + 0) * BB];
      const float x1 = Xp[(i + 1) * BB];
      const float x2 = Xp[(i + 2) * BB];
      const float x3 = Xp[(i + 3) * BB];
      const float4 a0 = *reinterpret_cast<const float4*>(A0 + i);
      const float4 a1 = *reinterpret_cast<const float4*>(A1 + i);
      r0a = fmaf(a0.x, x0, fmaf(a0.y, x1, r0a));
      r0b = fmaf(a0.z, x2, fmaf(a0.w, x3, r0b));
      r1a = fmaf(a1.x, x0, fmaf(a1.y, x1, r1a));
      r1b = fmaf(a1.z, x2, fmaf(a1.w, x3, r1b));
    }
    p1[w][0][l] = r0a + r0b;
    p1[w][1][l] = r1a + r1b;
    __syncthreads();
    if (w < 2) {
      const float s =
          ((p1[0][w][l] + p1[1][w][l]) + (p1[2][w][l] + p1[3][w][l])) +
          ((p1[4][w][l] + p1[5][w][l]) + (p1[6][w][l] + p1[7][w][l]));
      R[(m0 + w) * BB + l] = Y[l * MM + (m0 + w)] - s;
    }
  }
  grid.sync();

  // ---------- Phase 2: H1_t[b,n], z_t[b,n] ----------
  {
    const int b_l = w >> 2;
    const int mc = w & 3;
    const int nc = bid & 7;
    const int bp = bid >> 3;
    const int b = bp * 2 + b_l;
    const int n0 = nc * 128;
    const float* __restrict__ Ap = A + (size_t)(mc * 128) * NN + n0 + l * 2;
    const float* __restrict__ Rp = R + (size_t)(mc * 128) * BB + b;
    float s0 = 0.f, s1 = 0.f, s2 = 0.f, s3 = 0.f;
    float t0 = 0.f, t1 = 0.f, t2 = 0.f, t3 = 0.f;
    #pragma unroll 2
    for (int i = 0; i < 128; i += 4) {
      const float2 a0 = *reinterpret_cast<const float2*>(Ap + (size_t)(i + 0) * NN);
      const float2 a1 = *reinterpret_cast<const float2*>(Ap + (size_t)(i + 1) * NN);
      const float2 a2 = *reinterpret_cast<const float2*>(Ap + (size_t)(i + 2) * NN);
      const float2 a3 = *reinterpret_cast<const float2*>(Ap + (size_t)(i + 3) * NN);
      const float r0 = Rp[(i + 0) * BB];
      const float r1 = Rp[(i + 1) * BB];
      const float r2 = Rp[(i + 2) * BB];
      const float r3 = Rp[(i + 3) * BB];
      s0 = fmaf(a0.x, r0, s0); t0 = fmaf(a0.y, r0, t0);
      s1 = fmaf(a1.x, r1, s1); t1 = fmaf(a1.y, r1, t1);
      s2 = fmaf(a2.x, r2, s2); t2 = fmaf(a2.y, r2, t2);
      s3 = fmaf(a3.x, r3, s3); t3 = fmaf(a3.y, r3, t3);
    }
    p2[b_l][mc][l * 2 + 0] = (s0 + s1) + (s2 + s3);
    p2[b_l][mc][l * 2 + 1] = (t0 + t1) + (t2 + t3);
    __syncthreads();
    if (t < 256) {
      const int bl2 = t >> 7;
      const int nn = t & 127;
      const int bb = bp * 2 + bl2;
      const int n = n0 + nn;
      const float s = (p2[bl2][0][nn] + p2[bl2][1][nn]) +
                      (p2[bl2][2][nn] + p2[bl2][3][nn]);
      const float h = fmaf(ETA, s, X[n * BB + bb]);
      H1_t[bb * NN + n] = h;
      z_t[bb * NN + n] = fabsf(W[n] * h);
    }
  }
  grid.sync();

  // ---------- Phase 3: c_part[q][b][n], q-chunk of 256 j ----------
  {
    const int b = bid >> 2;
    const int q = bid & 3;
    if (t < 256) z4[t] = reinterpret_cast<const float4*>(z_t + b * NN)[t];
    __syncthreads();
    const float* zs = reinterpret_cast<const float*>(z4);
    const float zn0 = zs[t];
    const float zn1 = zs[t + 512];
    float c0 = 0.f, c1 = 0.f;
    const float4* zq = z4 + q * 64;
    #pragma unroll 4
    for (int i = 0; i < 64; ++i) {
      const float4 f = zq[i];
      c0 += (fabsf(zn0 - f.x) + fabsf(zn0 - f.y)) + (fabsf(zn0 - f.z) + fabsf(zn0 - f.w));
      c1 += (fabsf(zn1 - f.x) + fabsf(zn1 - f.y)) + (fabsf(zn1 - f.z) + fabsf(zn1 - f.w));
    }
    float* cp = c_part + q * (BB * NN) + b * NN;
    cp[t] = c0;
    cp[t + 512] = c1;
  }
  grid.sync();

  // ---------- Phase 4: softmax + mask + out (blocks 0..63) ----------
  if (bid < BB) {
    const int b = bid;
    const int BN = BB * NN;
    {
      const int i0 = b * NN + t;
      const int i1 = i0 + 512;
      const float cA = (c_part[i0] + c_part[i0 + BN]) +
                       (c_part[i0 + 2 * BN] + c_part[i0 + 3 * BN]);
      const float cB = (c_part[i1] + c_part[i1 + BN]) +
                       (c_part[i1 + 2 * BN] + c_part[i1 + 3 * BN]);
      zc_s[t] = make_float2(z_t[i0], cA);
      zc_s[t + 512] = make_float2(z_t[i1], cB);
    }
    __syncthreads();

    float zz[16], cc[16], mp[16];
    #pragma unroll
    for (int k = 0; k < 16; ++k) {
      const float2 v = zc_s[l + 64 * k];
      zz[k] = v.x;
      cc[k] = v.y;
      mp[k] = 0.f;
    }
    for (int s = w; s < SS; s += 8) {
      const float ks = (float)(NN + 1 - 2 * (s + 1));
      float lg[16];
      float mx = -INFINITY;
      #pragma unroll
      for (int k = 0; k < 16; ++k) {
        lg[k] = fmaf(ks, zz[k], -cc[k]);
        mx = fmaxf(mx, lg[k]);
      }
      #pragma unroll
      for (int off = 32; off > 0; off >>= 1)
        mx = fmaxf(mx, __shfl_xor(mx, off, 64));
      float sum = 0.f;
      #pragma unroll
      for (int k = 0; k < 16; ++k) {
        lg[k] = __expf(lg[k] - mx);
        sum += lg[k];
      }
      #pragma unroll
      for (int off = 32; off > 0; off >>= 1)
        sum += __shfl_xor(sum, off, 64);
      const float rs = 1.f / sum;
      #pragma unroll
      for (int k = 0; k < 16; ++k) mp[k] = fmaf(lg[k], rs, mp[k]);
    }
    #pragma unroll
    for (int k = 0; k < 16; ++k) mpart[w][l + 64 * k] = mp[k];
    __syncthreads();

    float m0 = 0.f, m1 = 0.f;
    #pragma unroll
    for (int u = 0; u < 8; ++u) {
      m0 += mpart[u][t];
      m1 += mpart[u][t + 512];
    }
    out[t * BB + b] = m0 * H1_t[b * NN + t];
    out[(t + 512) * BB + b] = m1 * H1_t[b * NN + t + 512];
  }
}

extern "C" void kernel_launch(void* const* d_in, const int* in_sizes, int n_in,
                              void* d_out, int out_size, void* d_ws, size_t ws_size,
                              hipStream_t stream) {
  const float* X = (const float*)d_in[0];
  const float* Y = (const float*)d_in[1];
  const float* A = (const float*)d_in[2];
  const float* W = (const float*)d_in[3];
  float* out = (float*)d_out;

  float* R = (float*)d_ws;                 // 32768 f
  float* z_t = R + MM * BB;                // 65536 f
  float* H1_t = z_t + NN * BB;             // 65536 f
  float* c_part = H1_t + NN * BB;          // 4*65536 f

  void* args[] = {(void*)&X, (void*)&Y, (void*)&A, (void*)&W,
                  (void*)&R, (void*)&z_t, (void*)&H1_t, (void*)&c_part,
                  (void*)&out};
  hipLaunchCooperativeKernel((void*)k_fused, dim3(256), dim3(512), args, 0,
                             stream);
}

// Round 6
// 66.517 us; speedup vs baseline: 1.9719x; 1.9719x over previous
//
#include <hip/hip_runtime.h>
#include <math.h>

#define MM 512
#define NN 1024
#define BB 64
#define SS 50
#define ETA 0.1f

// K1: R[m,b] = Y[b,m] - sum_n A[m,n]*X[n,b]
// grid 256, block (64,8). Block owns 2 m-rows; wave w sums n-chunk w (128 n);
// 8-way LDS tree reduce. (r4-proven)
__global__ __launch_bounds__(512) void k_r(const float* __restrict__ X,
                                           const float* __restrict__ Y,
                                           const float* __restrict__ A,
                                           float* __restrict__ R) {
  const int l = threadIdx.x;          // batch b
  const int w = threadIdx.y;          // n-chunk 0..7
  const int m0 = blockIdx.x * 2;
  __shared__ float part[8][2][BB];
  const float* __restrict__ Xp = X + w * 128 * BB + l;
  const float* __restrict__ A0 = A + (size_t)m0 * NN + w * 128;
  const float* __restrict__ A1 = A0 + NN;
  float r0a = 0.f, r0b = 0.f, r1a = 0.f, r1b = 0.f;
  #pragma unroll 8
  for (int i = 0; i < 128; i += 4) {
    const float x0 = Xp[(i + 0) * BB];
    const float x1 = Xp[(i + 1) * BB];
    const float x2 = Xp[(i + 2) * BB];
    const float x3 = Xp[(i + 3) * BB];
    const float4 a0 = *reinterpret_cast<const float4*>(A0 + i);
    const float4 a1 = *reinterpret_cast<const float4*>(A1 + i);
    r0a = fmaf(a0.x, x0, fmaf(a0.y, x1, r0a));
    r0b = fmaf(a0.z, x2, fmaf(a0.w, x3, r0b));
    r1a = fmaf(a1.x, x0, fmaf(a1.y, x1, r1a));
    r1b = fmaf(a1.z, x2, fmaf(a1.w, x3, r1b));
  }
  part[w][0][l] = r0a + r0b;
  part[w][1][l] = r1a + r1b;
  __syncthreads();
  if (w < 2) {
    const float s =
        ((part[0][w][l] + part[1][w][l]) + (part[2][w][l] + part[3][w][l])) +
        ((part[4][w][l] + part[5][w][l]) + (part[6][w][l] + part[7][w][l]));
    R[(m0 + w) * BB + l] = Y[l * MM + (m0 + w)] - s;
  }
}

// K2: per-batch fused. grid 64 (block = batch), block 512 (8 waves).
// Phases: stage Rs -> H1+z (thread owns n=2t,2t+1) -> c (brute, LDS
// broadcast) -> softmax (8 waves, fixed-order merge) -> out.
// Everything except A/X/R reads and the final out write stays in LDS.
__global__ __launch_bounds__(512) void k_fused(const float* __restrict__ X,
                                               const float* __restrict__ A,
                                               const float* __restrict__ R,
                                               const float* __restrict__ W,
                                               float* __restrict__ out) {
  const int b = blockIdx.x;
  const int t = threadIdx.x;   // 0..511
  const int l = t & 63;
  const int w = t >> 6;

  __shared__ float Rs[MM];
  __shared__ __align__(16) float zs[NN];
  __shared__ __align__(16) float cs[NN];
  __shared__ __align__(16) float h1s[NN];
  __shared__ float mpart[8][NN];

  // ---- stage R[:,b] (512 scattered 4B loads, independent) ----
  Rs[t] = R[t * BB + b];
  __syncthreads();

  // ---- H1 + z for n0 = 2t, n1 = 2t+1 ----
  float z0, z1;
  {
    const float2* __restrict__ A2 = reinterpret_cast<const float2*>(A) + t;
    const float4* __restrict__ R4 = reinterpret_cast<const float4*>(Rs);
    float s0 = 0.f, s1 = 0.f, s2 = 0.f, s3 = 0.f;
    float u0 = 0.f, u1 = 0.f, u2 = 0.f, u3 = 0.f;
    #pragma unroll 2
    for (int m = 0; m < MM; m += 4) {
      const float2 q0 = A2[(size_t)(m + 0) * (NN / 2)];
      const float2 q1 = A2[(size_t)(m + 1) * (NN / 2)];
      const float2 q2 = A2[(size_t)(m + 2) * (NN / 2)];
      const float2 q3 = A2[(size_t)(m + 3) * (NN / 2)];
      const float4 r = R4[m >> 2];
      s0 = fmaf(q0.x, r.x, s0); u0 = fmaf(q0.y, r.x, u0);
      s1 = fmaf(q1.x, r.y, s1); u1 = fmaf(q1.y, r.y, u1);
      s2 = fmaf(q2.x, r.z, s2); u2 = fmaf(q2.y, r.z, u2);
      s3 = fmaf(q3.x, r.w, s3); u3 = fmaf(q3.y, r.w, u3);
    }
    const float sum0 = (s0 + s1) + (s2 + s3);
    const float sum1 = (u0 + u1) + (u2 + u3);
    const float h0 = fmaf(ETA, sum0, X[(2 * t + 0) * BB + b]);
    const float h1 = fmaf(ETA, sum1, X[(2 * t + 1) * BB + b]);
    const float2 w2 = reinterpret_cast<const float2*>(W)[t];
    z0 = fabsf(w2.x * h0);
    z1 = fabsf(w2.y * h1);
    reinterpret_cast<float2*>(h1s)[t] = make_float2(h0, h1);
    reinterpret_cast<float2*>(zs)[t] = make_float2(z0, z1);
  }
  __syncthreads();

  // ---- c[n] = sum_j |z[n]-z[j]| for n0,n1; 4 j-chunk accumulators ----
  {
    const float4* __restrict__ zp = reinterpret_cast<const float4*>(zs);
    float ca[4], cb[4];
    #pragma unroll
    for (int g = 0; g < 4; ++g) {
      float x0 = 0.f, x1 = 0.f;
      #pragma unroll 4
      for (int i = 0; i < 64; ++i) {
        const float4 f = zp[g * 64 + i];
        x0 += (fabsf(z0 - f.x) + fabsf(z0 - f.y)) +
              (fabsf(z0 - f.z) + fabsf(z0 - f.w));
        x1 += (fabsf(z1 - f.x) + fabsf(z1 - f.y)) +
              (fabsf(z1 - f.z) + fabsf(z1 - f.w));
      }
      ca[g] = x0;
      cb[g] = x1;
    }
    const float c0 = (ca[0] + ca[1]) + (ca[2] + ca[3]);
    const float c1 = (cb[0] + cb[1]) + (cb[2] + cb[3]);
    reinterpret_cast<float2*>(cs)[t] = make_float2(c0, c1);
  }
  __syncthreads();

  // ---- softmax over s = w, w+8, ... ; fixed-order merge via mpart ----
  {
    float zz[16], cc[16], mp[16];
    #pragma unroll
    for (int k = 0; k < 16; ++k) {
      zz[k] = zs[l + 64 * k];
      cc[k] = cs[l + 64 * k];
      mp[k] = 0.f;
    }
    for (int s = w; s < SS; s += 8) {
      const float ks = (float)(NN + 1 - 2 * (s + 1));
      float lg[16];
      float mx = -INFINITY;
      #pragma unroll
      for (int k = 0; k < 16; ++k) {
        lg[k] = fmaf(ks, zz[k], -cc[k]);
        mx = fmaxf(mx, lg[k]);
      }
      #pragma unroll
      for (int off = 32; off > 0; off >>= 1)
        mx = fmaxf(mx, __shfl_xor(mx, off, 64));
      float sum = 0.f;
      #pragma unroll
      for (int k = 0; k < 16; ++k) {
        lg[k] = __expf(lg[k] - mx);
        sum += lg[k];
      }
      #pragma unroll
      for (int off = 32; off > 0; off >>= 1)
        sum += __shfl_xor(sum, off, 64);
      const float rs = 1.f / sum;
      #pragma unroll
      for (int k = 0; k < 16; ++k) mp[k] = fmaf(lg[k], rs, mp[k]);
    }
    #pragma unroll
    for (int k = 0; k < 16; ++k) mpart[w][l + 64 * k] = mp[k];
  }
  __syncthreads();

  // ---- merge mask (fixed order) + write out ----
  {
    float m0 = 0.f, m1 = 0.f;
    #pragma unroll
    for (int u = 0; u < 8; ++u) {
      m0 += mpart[u][t];
      m1 += mpart[u][t + 512];
    }
    out[t * BB + b] = m0 * h1s[t];
    out[(t + 512) * BB + b] = m1 * h1s[t + 512];
  }
}

extern "C" void kernel_launch(void* const* d_in, const int* in_sizes, int n_in,
                              void* d_out, int out_size, void* d_ws, size_t ws_size,
                              hipStream_t stream) {
  const float* X = (const float*)d_in[0];  // (N,B)
  const float* Y = (const float*)d_in[1];  // (B,M)
  const float* A = (const float*)d_in[2];  // (M,N)
  const float* W = (const float*)d_in[3];  // (N,)
  float* out = (float*)d_out;              // (N,B)

  float* R = (float*)d_ws;                 // (M,B) = 32768 f

  k_r    <<<dim3(MM / 2), dim3(64, 8), 0, stream>>>(X, Y, A, R);
  k_fused<<<dim3(BB), dim3(512), 0, stream>>>(X, A, R, W, out);
}